// Round 8
// baseline (265.478 us; speedup 1.0000x reference)
//
#include <hip/hip_runtime.h>
#include <hip/hip_bf16.h>

#define NNODES 100000
#define NEDGES 1600000
#define IN_CH 128
#define HID 64
#define NC 40
#define NPAD 100352   // NNODES padded to multiple of 256
#define NBUK 196      // ceil(100000 / 512) dst-buckets of 512 nodes
#define CAP 9216      // per-bucket tmp capacity (mean 8192, sigma ~90 -> 11 sigma)
#define BCHUNK 4096
#define NBIN 391      // ceil(NEDGES / BCHUNK)

typedef unsigned short ushort_t;
typedef unsigned int uint_t;
typedef __attribute__((ext_vector_type(8))) short short8;
typedef __attribute__((ext_vector_type(4))) float floatx4;
typedef __attribute__((ext_vector_type(2))) float f32x2;

__device__ __forceinline__ ushort_t f2bf(float f) {
    union { float ff; unsigned int i; } t;
    t.ff = f;
    unsigned int r = t.i + 0x7fff + ((t.i >> 16) & 1);  // RNE
    return (ushort_t)(r >> 16);
}
// acc += unpack(packed bf16x2); vector += encourages v_pk_add_f32
__device__ __forceinline__ void acc2(f32x2& a, uint_t p) {
    union { unsigned int i; float f; } lo, hi;
    lo.i = p << 16;
    hi.i = p & 0xffff0000u;
    f32x2 v = {lo.f, hi.f};
    a += v;
}

// ---- bin edges into bucket-major tmp; entry: src(17b) | local_d(9b)<<17 ----
// gcur is count-only (zeroed by hipMemsetAsync); segment base = b*CAP + count.
// Also accumulates per-node in-degree (deg, zeroed by the same memset) so the
// gemm1 half of k_sg can derive dinv without waiting for the sort half.
// Extra block (blockIdx == NBIN): Wp swizzle + hb zero-sentinel (row n).
__global__ __launch_bounds__(256) void k_bin0(
    const int* __restrict__ srcs, const int* __restrict__ dsts,
    int* __restrict__ gcur, int* __restrict__ deg, uint_t* __restrict__ tmp, int e,
    const float* __restrict__ W1, ushort_t* __restrict__ Wp,
    ushort_t* __restrict__ hb, int n)
{
    __shared__ uint_t pk[BCHUNK];    // 16 KB
    __shared__ ushort_t bk[BCHUNK];  // 8 KB
    __shared__ int hist[NBUK];
    __shared__ int base[NBUK];
    int t = threadIdx.x;
    if (blockIdx.x >= NBIN) {        // side-work block (uniform branch)
        for (int i = t; i < IN_CH * HID; i += 256) {
            int j = i & 7;
            int m = (i >> 3) & 15;
            int ct = (i >> 7) & 3;
            int quad = (i >> 9) & 3;
            int kc = i >> 11;
            int k = kc * 32 + quad * 8 + j;
            int c = ct * 16 + m;
            Wp[i] = f2bf(W1[k * HID + c]);
        }
        uint_t* hbz = (uint_t*)(hb + (size_t)n * HID);
        if (t < 32) hbz[t] = 0;      // 64 bf16 zeros (sentinel row n)
        return;
    }
    int begin = blockIdx.x * BCHUNK;
    int cnt = e - begin; if (cnt > BCHUNK) cnt = BCHUNK;

    for (int i = t; i < NBUK; i += 256) hist[i] = 0;
    __syncthreads();
    for (int j = t; j < cnt; j += 256) {
        int d = dsts[begin + j];
        int s = srcs[begin + j];
        int b = d >> 9;
        pk[j] = (uint_t)s | ((uint_t)(d & 511) << 17);
        bk[j] = (ushort_t)b;
        atomicAdd(&hist[b], 1);
        atomicAdd(&deg[d], 1);       // per-node in-degree for early dinv
    }
    __syncthreads();
    for (int i = t; i < NBUK; i += 256) {
        base[i] = i * CAP + atomicAdd(&gcur[i], hist[i]);  // reserve segment
        hist[i] = 0;                                       // reuse as rank cursor
    }
    __syncthreads();
    for (int j = t; j < cnt; j += 256) {
        int b = bk[j];
        int r = atomicAdd(&hist[b], 1);
        int pos = base[b] + r;
        if (pos < (b + 1) * CAP) tmp[pos] = pk[j];  // burst writes; guard vs overflow
    }
}

// ---- merged k_sg: blocks 0..NBUK-1 = sort; the rest = GEMM1 ----
// The two halves are independent (gemm1 derives dinv from deg) and overlap on
// the machine instead of running serially with a launch gap between them.
__global__ __launch_bounds__(256) void k_sg(
    const uint_t* __restrict__ tmp, const int* __restrict__ gcur,
    int* __restrict__ row_start, float* __restrict__ dinv,
    uint_t* __restrict__ es, int n, int e,
    const float* __restrict__ x, const ushort_t* __restrict__ Wp,
    const int* __restrict__ deg, ushort_t* __restrict__ hw1)
{
    __shared__ int cnt[512];
    __shared__ int sc[512];
    __shared__ int red[256];
    int t = threadIdx.x;
    if (blockIdx.x < NBUK) {
        // ---------------- sort half ----------------
        int b = blockIdx.x;
        int d0 = b << 9;
        int total = gcur[b];
        if (total > CAP) total = CAP;
        // gb = exclusive prefix over bucket totals
        int part = 0;
        for (int i = t; i < b; i += 256) part += gcur[i];
        red[t] = part;
        cnt[t] = 0; cnt[t + 256] = 0;
        __syncthreads();
        for (int off = 128; off > 0; off >>= 1) {
            if (t < off) red[t] += red[t + off];
            __syncthreads();
        }
        int gb = red[0];
        // count per node
        const uint_t* seg = tmp + b * CAP;
        for (int j = t; j < total; j += 256)
            atomicAdd(&cnt[seg[j] >> 17], 1);
        __syncthreads();
        sc[t] = cnt[t]; sc[t + 256] = cnt[t + 256];
        __syncthreads();
        for (int off = 1; off < 512; off <<= 1) {
            int v0 = (t >= off) ? sc[t - off] : 0;
            int i1 = t + 256;
            int v1 = (i1 >= off) ? sc[i1 - off] : 0;
            __syncthreads();
            sc[t] += v0; sc[i1] += v1;
            __syncthreads();
        }
#pragma unroll
        for (int q = 0; q < 2; ++q) {
            int i = t + q * 256;
            int node = d0 + i;
            int start = gb + sc[i] - cnt[i];
            if (node < n) {
                row_start[node] = start;
                dinv[node] = rsqrtf((float)cnt[i] + 1.0f);
            }
            cnt[i] = start;   // reuse cnt as scatter cursor (own-thread overwrite)
        }
        __syncthreads();
        // scatter to final CSR order
        for (int j = t; j < total; j += 256) {
            uint_t p = seg[j];
            int ld = (int)(p >> 17);
            int pos = atomicAdd(&cnt[ld], 1);
            es[pos] = p & 0x1FFFFu;
        }
        if (b == NBUK - 1 && t == 0) row_start[n] = e;
        return;
    }
    // ---------------- GEMM1 half: hw1 = bf16(dinv * (x @ W1)) via MFMA ----------------
    int blk = blockIdx.x - NBUK;
    int wave = t >> 6;
    int lane = t & 63;
    int m = lane & 15;
    int quad = lane >> 4;
    int row = blk * 64 + wave * 16 + m;
    int rowc = row < n ? row : (n - 1);
    const float* xr = x + (size_t)rowc * IN_CH + quad * 8;

    floatx4 acc[4];
#pragma unroll
    for (int ct = 0; ct < 4; ++ct) acc[ct] = (floatx4){0.f, 0.f, 0.f, 0.f};

#pragma unroll
    for (int kc = 0; kc < 4; ++kc) {
        float4 xa = *(const float4*)(xr + kc * 32);
        float4 xb = *(const float4*)(xr + kc * 32 + 4);
        short8 a;
        a[0] = (short)f2bf(xa.x); a[1] = (short)f2bf(xa.y);
        a[2] = (short)f2bf(xa.z); a[3] = (short)f2bf(xa.w);
        a[4] = (short)f2bf(xb.x); a[5] = (short)f2bf(xb.y);
        a[6] = (short)f2bf(xb.z); a[7] = (short)f2bf(xb.w);
#pragma unroll
        for (int ct = 0; ct < 4; ++ct) {
            short8 b = *(const short8*)(Wp + ((((kc * 4 + quad) * 4 + ct) * 16 + m) << 3));
            acc[ct] = __builtin_amdgcn_mfma_f32_16x16x32_bf16(a, b, acc[ct], 0, 0, 0);
        }
    }
    int r0 = blk * 64 + wave * 16 + quad * 4;
#pragma unroll
    for (int r = 0; r < 4; ++r) {
        int rr = r0 + r;
        if (rr < n) {
            float di = rsqrtf((float)deg[rr] + 1.0f);   // dinv from deg (no sort dep)
            ushort_t* o = hw1 + (size_t)rr * HID + m;
#pragma unroll
            for (int ct = 0; ct < 4; ++ct) o[ct * 16] = f2bf(acc[ct][r] * di);
        } else if (rr == n) {
            ushort_t* o = hw1 + (size_t)n * HID + m;
#pragma unroll
            for (int ct = 0; ct < 4; ++ct) o[ct * 16] = 0;
        }
    }
}

// ---- agg1: one OCTET (8 lanes) per node (round-6 structure, best measured) ----
// Row = 64ch bf16 = 128 B = 8 lanes x dwordx4; one gather fetches 8 rows; 8
// node-chains per wave. Uniform 8-edge windows: sentinel row n (all zero)
// absorbs padding. No LDS, no barrier, low VGPR -> high occupancy.
__global__ __launch_bounds__(256) void k_agg1(
    const int* __restrict__ row_start, const uint_t* __restrict__ es,
    const float* __restrict__ dinv, const uint_t* __restrict__ hw1u,
    const float* __restrict__ b1, ushort_t* __restrict__ hb, int n)
{
    int lane = threadIdx.x & 63;
    int obase = lane & 56;              // octet's first lane in the wave
    int ol = lane & 7;
    int node = blockIdx.x * 32 + (threadIdx.x >> 3);
    bool valid = node < n;
    int rs = valid ? row_start[node] : 0;
    int re = valid ? row_start[node + 1] : 0;
    float di = valid ? dinv[node] : 0.f;
    int selfrow = valid ? node : n;

    f32x2 c0, c1, c2, c3;
    {
        uint4 sp = *(const uint4*)(hw1u + (size_t)selfrow * 32 + ol * 4);
        c0 = (f32x2){0.f, 0.f}; c1 = c0; c2 = c0; c3 = c0;
        acc2(c0, sp.x); acc2(c1, sp.y); acc2(c2, sp.z); acc2(c3, sp.w);
    }
    for (int base = rs; base < re; base += 8) {
        int idx = base + ol;
        int el = (idx < re) ? (int)es[idx] : n;   // pad -> zero sentinel
        uint4 p[8];
#pragma unroll
        for (int b = 0; b < 8; ++b) {
            int s = __shfl(el, obase + b);
            p[b] = *(const uint4*)(hw1u + (size_t)s * 32 + ol * 4);
        }
#pragma unroll
        for (int b = 0; b < 8; ++b) {
            acc2(c0, p[b].x); acc2(c1, p[b].y);
            acc2(c2, p[b].z); acc2(c3, p[b].w);
        }
    }
    if (valid) {
        float4 bb0 = ((const float4*)b1)[ol * 2];
        float4 bb1 = ((const float4*)b1)[ol * 2 + 1];
        float h0 = fmaxf(c0.x * di + bb0.x, 0.f);
        float h1 = fmaxf(c0.y * di + bb0.y, 0.f);
        float h2 = fmaxf(c1.x * di + bb0.z, 0.f);
        float h3 = fmaxf(c1.y * di + bb0.w, 0.f);
        float h4 = fmaxf(c2.x * di + bb1.x, 0.f);
        float h5 = fmaxf(c2.y * di + bb1.y, 0.f);
        float h6 = fmaxf(c3.x * di + bb1.z, 0.f);
        float h7 = fmaxf(c3.y * di + bb1.w, 0.f);
        // hb = dinv * h (source weight for layer-2 aggregation), bf16-packed
        uint4 st;
        st.x = (uint_t)f2bf(h0 * di) | ((uint_t)f2bf(h1 * di) << 16);
        st.y = (uint_t)f2bf(h2 * di) | ((uint_t)f2bf(h3 * di) << 16);
        st.z = (uint_t)f2bf(h4 * di) | ((uint_t)f2bf(h5 * di) << 16);
        st.w = (uint_t)f2bf(h6 * di) | ((uint_t)f2bf(h7 * di) << 16);
        *(uint4*)(hb + (size_t)node * HID + ol * 8) = st;
    }
}

// ---- agg2 + fused GEMM2: octet gather over hb rows, then same-wave LDS dot ----
// (round-6 structure, best measured). hagg stays in LDS; out written directly.
__global__ __launch_bounds__(256) void k_agg2(
    const int* __restrict__ row_start, const uint_t* __restrict__ es,
    const float* __restrict__ dinv, const uint_t* __restrict__ hbu,
    const float* __restrict__ W2, const float* __restrict__ b2,
    float* __restrict__ out, int n)
{
    __shared__ float wsm[HID * NC];   // 10 KB, W2 row-major [64][40]
    __shared__ float hsm[32][68];     // 32 nodes x 64ch (+pad)
    for (int i = threadIdx.x; i < HID * NC; i += 256) wsm[i] = W2[i];
    __syncthreads();

    int lane = threadIdx.x & 63;
    int obase = lane & 56;
    int ol = lane & 7;
    int slot = threadIdx.x >> 3;        // node slot within block (0..31)
    int node = blockIdx.x * 32 + slot;
    bool valid = node < n;
    int rs = valid ? row_start[node] : 0;
    int re = valid ? row_start[node + 1] : 0;
    float di = valid ? dinv[node] : 0.f;
    int selfrow = valid ? node : n;

    f32x2 c0, c1, c2, c3;
    {
        uint4 sp = *(const uint4*)(hbu + (size_t)selfrow * 32 + ol * 4);
        c0 = (f32x2){0.f, 0.f}; c1 = c0; c2 = c0; c3 = c0;
        acc2(c0, sp.x); acc2(c1, sp.y); acc2(c2, sp.z); acc2(c3, sp.w);
    }
    for (int base = rs; base < re; base += 8) {
        int idx = base + ol;
        int el = (idx < re) ? (int)es[idx] : n;   // pad -> zero sentinel
        uint4 p[8];
#pragma unroll
        for (int b = 0; b < 8; ++b) {
            int s = __shfl(el, obase + b);
            p[b] = *(const uint4*)(hbu + (size_t)s * 32 + ol * 4);
        }
#pragma unroll
        for (int b = 0; b < 8; ++b) {
            acc2(c0, p[b].x); acc2(c1, p[b].y);
            acc2(c2, p[b].z); acc2(c3, p[b].w);
        }
    }
    // hagg row (f32) -> LDS; garbage for invalid nodes (never stored to out)
    {
        float4 g0, g1;
        g0.x = c0.x * di; g0.y = c0.y * di; g0.z = c1.x * di; g0.w = c1.y * di;
        g1.x = c2.x * di; g1.y = c2.y * di; g1.z = c3.x * di; g1.w = c3.y * di;
        *(float4*)&hsm[slot][ol * 8] = g0;
        *(float4*)&hsm[slot][ol * 8 + 4] = g1;
    }
    // fused GEMM2: two passes of 4-node quarter-wave dot over the wave's rows
    int w8 = (threadIdx.x >> 6) * 8;    // wave's first slot
    int qm = lane >> 4;                 // quarter 0..3
    int lq = lane & 15;
    int lw = (lq < 10) ? lq : 0;
    const float4* w4 = (const float4*)wsm;     // [64][10] float4
#pragma unroll
    for (int pass = 0; pass < 2; ++pass) {
        int slot2 = w8 + pass * 4 + qm;
        int node2 = blockIdx.x * 32 + slot2;
        float4 acc = ((const float4*)b2)[lw];  // b2 as accumulator init
#pragma unroll 4
        for (int k4 = 0; k4 < 16; ++k4) {
            float4 hk = *(const float4*)&hsm[slot2][k4 * 4];
            float4 w0 = w4[(k4 * 4 + 0) * 10 + lw];
            float4 w1 = w4[(k4 * 4 + 1) * 10 + lw];
            float4 w2 = w4[(k4 * 4 + 2) * 10 + lw];
            float4 w3 = w4[(k4 * 4 + 3) * 10 + lw];
            acc.x += hk.x * w0.x + hk.y * w1.x + hk.z * w2.x + hk.w * w3.x;
            acc.y += hk.x * w0.y + hk.y * w1.y + hk.z * w2.y + hk.w * w3.y;
            acc.z += hk.x * w0.z + hk.y * w1.z + hk.z * w2.z + hk.w * w3.z;
            acc.w += hk.x * w0.w + hk.y * w1.w + hk.z * w2.w + hk.w * w3.w;
        }
        if (node2 < n && lq < 10)
            *(float4*)(out + (size_t)node2 * NC + lq * 4) = acc;
    }
}

extern "C" void kernel_launch(void* const* d_in, const int* in_sizes, int n_in,
                              void* d_out, int out_size, void* d_ws, size_t ws_size,
                              hipStream_t stream) {
    const float* x  = (const float*)d_in[0];   // f32 [N,128]
    const int* edge = (const int*)d_in[1];     // int32 [2,E]
    const float* W1 = (const float*)d_in[2];   // f32 [128,64]
    const float* b1 = (const float*)d_in[3];   // f32 [64]
    const float* W2 = (const float*)d_in[4];   // f32 [64,40]
    const float* b2 = (const float*)d_in[5];   // f32 [40]
    float* out      = (float*)d_out;           // f32 [N,40]

    const int n = in_sizes[0] / IN_CH;   // 100000
    const int e = in_sizes[1] / 2;       // 1600000
    const int* srcs = edge;
    const int* dsts = edge + e;

    // workspace layout (all segments 16B-aligned); gcur+deg are one memset region
    int*      gcur      = (int*)d_ws;                       // 256
    int*      deg       = gcur + 256;                       // NPAD
    int*      row_start = deg + NPAD;                       // NPAD (needs n+1)
    float*    dinv      = (float*)(row_start + NPAD);       // NPAD
    uint_t*   tmp       = (uint_t*)(dinv + NPAD);           // NBUK*CAP packed 4B
    uint_t*   es        = tmp + (size_t)NBUK * CAP;         // NEDGES src-only 4B
    ushort_t* Wp        = (ushort_t*)(es + NEDGES);         // 8192 bf16
    ushort_t* hw1       = Wp + 8192;                        // (N+1)*64 bf16 (sentinel row n)
    ushort_t* hb        = hw1 + (size_t)(NNODES + 1) * HID; // (N+1)*64 bf16 (sentinel row n)

    hipMemsetAsync(gcur, 0, (256 + NPAD) * sizeof(int), stream);  // gcur + deg
    k_bin0<<<NBIN + 1, 256, 0, stream>>>(srcs, dsts, gcur, deg, tmp, e, W1, Wp, hb, n);
    k_sg<<<NBUK + (n + 63) / 64, 256, 0, stream>>>(tmp, gcur, row_start, dinv, es, n, e,
                                                   x, Wp, deg, hw1);
    k_agg1<<<(n + 31) / 32, 256, 0, stream>>>(row_start, es, dinv, (const uint_t*)hw1, b1, hb, n);
    k_agg2<<<(n + 31) / 32, 256, 0, stream>>>(row_start, es, dinv, (const uint_t*)hb, W2, b2, out, n);
}

// Round 9
// 214.062 us; speedup vs baseline: 1.2402x; 1.2402x over previous
//
#include <hip/hip_runtime.h>
#include <hip/hip_bf16.h>

#define NNODES 100000
#define NEDGES 1600000
#define IN_CH 128
#define HID 64
#define NC 40
#define NPAD 100352   // NNODES padded to multiple of 256
#define NBUK 196      // ceil(100000 / 512) dst-buckets of 512 nodes
#define CAP 9216      // per-bucket tmp capacity (mean 8192, sigma ~90 -> 11 sigma)
#define BCHUNK 4096
#define NBIN 391      // ceil(NEDGES / BCHUNK)

typedef unsigned short ushort_t;
typedef unsigned int uint_t;
typedef __attribute__((ext_vector_type(8))) short short8;
typedef __attribute__((ext_vector_type(4))) float floatx4;
typedef __attribute__((ext_vector_type(2))) float f32x2;

__device__ __forceinline__ ushort_t f2bf(float f) {
    union { float ff; unsigned int i; } t;
    t.ff = f;
    unsigned int r = t.i + 0x7fff + ((t.i >> 16) & 1);  // RNE
    return (ushort_t)(r >> 16);
}
// acc += unpack(packed bf16x2); vector += encourages v_pk_add_f32
__device__ __forceinline__ void acc2(f32x2& a, uint_t p) {
    union { unsigned int i; float f; } lo, hi;
    lo.i = p << 16;
    hi.i = p & 0xffff0000u;
    f32x2 v = {lo.f, hi.f};
    a += v;
}

// ---- bin edges into bucket-major tmp; entry: src(17b) | local_d(9b)<<17 ----
// gcur is count-only (zeroed by hipMemsetAsync); segment base = b*CAP + count.
// NEW: block-local bucket sort in LDS before write-out, so tmp stores are
// contiguous runs per bucket (round-8 PMC: scattered 4B stores cost 58 MB
// WRITE_SIZE for 6.4 MB of data -> ~9x write amplification).
// Extra block (blockIdx == NBIN): Wp swizzle + hb zero-sentinel (row n).
__global__ __launch_bounds__(256) void k_bin0(
    const int* __restrict__ srcs, const int* __restrict__ dsts,
    int* __restrict__ gcur, uint_t* __restrict__ tmp, int e,
    const float* __restrict__ W1, ushort_t* __restrict__ Wp,
    ushort_t* __restrict__ hb, int n)
{
    __shared__ uint_t pk[BCHUNK];    // 16 KB (input order)
    __shared__ ushort_t bk[BCHUNK];  // 8 KB
    __shared__ uint_t spk[BCHUNK];   // 16 KB (bucket-sorted)
    __shared__ ushort_t sb[BCHUNK];  // 8 KB bucket id per sorted slot
    __shared__ int hist[NBUK];
    __shared__ int lscan[NBUK];      // local exclusive scan over buckets
    __shared__ int base[NBUK];       // global base per bucket
    __shared__ int sc2[256];
    int t = threadIdx.x;
    if (blockIdx.x >= NBIN) {        // side-work block (uniform branch)
        for (int i = t; i < IN_CH * HID; i += 256) {
            int j = i & 7;
            int m = (i >> 3) & 15;
            int ct = (i >> 7) & 3;
            int quad = (i >> 9) & 3;
            int kc = i >> 11;
            int k = kc * 32 + quad * 8 + j;
            int c = ct * 16 + m;
            Wp[i] = f2bf(W1[k * HID + c]);
        }
        uint_t* hbz = (uint_t*)(hb + (size_t)n * HID);
        if (t < 32) hbz[t] = 0;      // 64 bf16 zeros (sentinel row n)
        return;
    }
    int begin = blockIdx.x * BCHUNK;
    int cnt = e - begin; if (cnt > BCHUNK) cnt = BCHUNK;

    for (int i = t; i < NBUK; i += 256) hist[i] = 0;
    __syncthreads();
    // pass 1: load + per-bucket count
    for (int j = t; j < cnt; j += 256) {
        int d = dsts[begin + j];
        int s = srcs[begin + j];
        int b = d >> 9;
        pk[j] = (uint_t)s | ((uint_t)(d & 511) << 17);
        bk[j] = (ushort_t)b;
        atomicAdd(&hist[b], 1);
    }
    __syncthreads();
    // pass 2: local scan (196 buckets) + global segment reservation
    int c = (t < NBUK) ? hist[t] : 0;
    sc2[t] = c;
    __syncthreads();
    for (int off = 1; off < 256; off <<= 1) {
        int v = (t >= off) ? sc2[t - off] : 0;
        __syncthreads();
        sc2[t] += v;
        __syncthreads();
    }
    if (t < NBUK) {
        lscan[t] = sc2[t] - c;
        base[t] = t * CAP + atomicAdd(&gcur[t], c);
        hist[t] = 0;                 // reuse as rank cursor
    }
    __syncthreads();
    // pass 3: rank-scatter into sorted LDS buffer
    for (int j = t; j < cnt; j += 256) {
        int b = bk[j];
        int r = atomicAdd(&hist[b], 1);
        int slot = lscan[b] + r;
        spk[slot] = pk[j];
        sb[slot] = (ushort_t)b;
    }
    __syncthreads();
    // pass 4: linear write-out (contiguous run per bucket)
    for (int j = t; j < cnt; j += 256) {
        int b = sb[j];
        int pos = base[b] + (j - lscan[b]);
        if (pos < (b + 1) * CAP) tmp[pos] = spk[j];  // guard vs overflow
    }
}

// ---- merged sort: per-bucket count + scan + row_start/dinv + scatter to es ----
// NEW: scatter to LDS staging (block's whole output segment), then fully
// coalesced linear copy to es (kills the random-4B-store write amplification).
__global__ __launch_bounds__(256) void k_sort(
    const uint_t* __restrict__ tmp, const int* __restrict__ gcur,
    int* __restrict__ row_start, float* __restrict__ dinv,
    uint_t* __restrict__ es, int n, int e)
{
    __shared__ int cnt[512];
    __shared__ int sc[512];
    __shared__ int red[256];
    __shared__ uint_t esl[CAP];   // 36 KB staging (total <= CAP)
    int t = threadIdx.x;
    int b = blockIdx.x;
    int d0 = b << 9;
    int total = gcur[b];
    if (total > CAP) total = CAP;
    // gb = exclusive prefix over bucket totals
    int part = 0;
    for (int i = t; i < b; i += 256) part += gcur[i];
    red[t] = part;
    cnt[t] = 0; cnt[t + 256] = 0;
    __syncthreads();
    for (int off = 128; off > 0; off >>= 1) {
        if (t < off) red[t] += red[t + off];
        __syncthreads();
    }
    int gb = red[0];
    // count per node
    const uint_t* seg = tmp + b * CAP;
    for (int j = t; j < total; j += 256)
        atomicAdd(&cnt[seg[j] >> 17], 1);
    __syncthreads();
    sc[t] = cnt[t]; sc[t + 256] = cnt[t + 256];
    __syncthreads();
    for (int off = 1; off < 512; off <<= 1) {
        int v0 = (t >= off) ? sc[t - off] : 0;
        int i1 = t + 256;
        int v1 = (i1 >= off) ? sc[i1 - off] : 0;
        __syncthreads();
        sc[t] += v0; sc[i1] += v1;
        __syncthreads();
    }
#pragma unroll
    for (int q = 0; q < 2; ++q) {
        int i = t + q * 256;
        int node = d0 + i;
        int start = gb + sc[i] - cnt[i];
        if (node < n) {
            row_start[node] = start;
            dinv[node] = rsqrtf((float)cnt[i] + 1.0f);
        }
        cnt[i] = start - gb;   // reuse cnt as LOCAL scatter cursor (segment-relative)
    }
    __syncthreads();
    // scatter to LDS staging in final CSR order
    for (int j = t; j < total; j += 256) {
        uint_t p = seg[j];
        int ld = (int)(p >> 17);
        int pos = atomicAdd(&cnt[ld], 1);
        esl[pos] = p & 0x1FFFFu;
    }
    __syncthreads();
    // coalesced linear write-out
    for (int j = t; j < total; j += 256) es[gb + j] = esl[j];
    if (b == NBUK - 1 && t == 0) row_start[n] = e;
}

// ---- GEMM1: hw1 = bf16(dinv * (x @ W1)) via MFMA; row n = zero sentinel ----
__global__ __launch_bounds__(256) void k_gemm1(
    const float* __restrict__ x, const ushort_t* __restrict__ Wp,
    const float* __restrict__ dinv, ushort_t* __restrict__ hw1, int n)
{
    int wave = threadIdx.x >> 6;
    int lane = threadIdx.x & 63;
    int m = lane & 15;
    int quad = lane >> 4;
    int row = blockIdx.x * 64 + wave * 16 + m;
    int rowc = row < n ? row : (n - 1);
    const float* xr = x + (size_t)rowc * IN_CH + quad * 8;

    floatx4 acc[4];
#pragma unroll
    for (int ct = 0; ct < 4; ++ct) acc[ct] = (floatx4){0.f, 0.f, 0.f, 0.f};

#pragma unroll
    for (int kc = 0; kc < 4; ++kc) {
        float4 xa = *(const float4*)(xr + kc * 32);
        float4 xb = *(const float4*)(xr + kc * 32 + 4);
        short8 a;
        a[0] = (short)f2bf(xa.x); a[1] = (short)f2bf(xa.y);
        a[2] = (short)f2bf(xa.z); a[3] = (short)f2bf(xa.w);
        a[4] = (short)f2bf(xb.x); a[5] = (short)f2bf(xb.y);
        a[6] = (short)f2bf(xb.z); a[7] = (short)f2bf(xb.w);
#pragma unroll
        for (int ct = 0; ct < 4; ++ct) {
            short8 b = *(const short8*)(Wp + ((((kc * 4 + quad) * 4 + ct) * 16 + m) << 3));
            acc[ct] = __builtin_amdgcn_mfma_f32_16x16x32_bf16(a, b, acc[ct], 0, 0, 0);
        }
    }
    int r0 = blockIdx.x * 64 + wave * 16 + quad * 4;
#pragma unroll
    for (int r = 0; r < 4; ++r) {
        int rr = r0 + r;
        if (rr < n) {
            float di = dinv[rr];
            ushort_t* o = hw1 + (size_t)rr * HID + m;
#pragma unroll
            for (int ct = 0; ct < 4; ++ct) o[ct * 16] = f2bf(acc[ct][r] * di);
        } else if (rr == n) {
            ushort_t* o = hw1 + (size_t)n * HID + m;
#pragma unroll
            for (int ct = 0; ct < 4; ++ct) o[ct * 16] = 0;
        }
    }
}

// ---- agg1: one OCTET (8 lanes) per node (round-6 structure, best measured) ----
// Row = 64ch bf16 = 128 B = 8 lanes x dwordx4; one gather fetches 8 rows; 8
// node-chains per wave. Uniform 8-edge windows: sentinel row n (all zero)
// absorbs padding. No LDS, no barrier, low VGPR -> high occupancy.
__global__ __launch_bounds__(256) void k_agg1(
    const int* __restrict__ row_start, const uint_t* __restrict__ es,
    const float* __restrict__ dinv, const uint_t* __restrict__ hw1u,
    const float* __restrict__ b1, ushort_t* __restrict__ hb, int n)
{
    int lane = threadIdx.x & 63;
    int obase = lane & 56;              // octet's first lane in the wave
    int ol = lane & 7;
    int node = blockIdx.x * 32 + (threadIdx.x >> 3);
    bool valid = node < n;
    int rs = valid ? row_start[node] : 0;
    int re = valid ? row_start[node + 1] : 0;
    float di = valid ? dinv[node] : 0.f;
    int selfrow = valid ? node : n;

    f32x2 c0, c1, c2, c3;
    {
        uint4 sp = *(const uint4*)(hw1u + (size_t)selfrow * 32 + ol * 4);
        c0 = (f32x2){0.f, 0.f}; c1 = c0; c2 = c0; c3 = c0;
        acc2(c0, sp.x); acc2(c1, sp.y); acc2(c2, sp.z); acc2(c3, sp.w);
    }
    for (int base = rs; base < re; base += 8) {
        int idx = base + ol;
        int el = (idx < re) ? (int)es[idx] : n;   // pad -> zero sentinel
        uint4 p[8];
#pragma unroll
        for (int b = 0; b < 8; ++b) {
            int s = __shfl(el, obase + b);
            p[b] = *(const uint4*)(hw1u + (size_t)s * 32 + ol * 4);
        }
#pragma unroll
        for (int b = 0; b < 8; ++b) {
            acc2(c0, p[b].x); acc2(c1, p[b].y);
            acc2(c2, p[b].z); acc2(c3, p[b].w);
        }
    }
    if (valid) {
        float4 bb0 = ((const float4*)b1)[ol * 2];
        float4 bb1 = ((const float4*)b1)[ol * 2 + 1];
        float h0 = fmaxf(c0.x * di + bb0.x, 0.f);
        float h1 = fmaxf(c0.y * di + bb0.y, 0.f);
        float h2 = fmaxf(c1.x * di + bb0.z, 0.f);
        float h3 = fmaxf(c1.y * di + bb0.w, 0.f);
        float h4 = fmaxf(c2.x * di + bb1.x, 0.f);
        float h5 = fmaxf(c2.y * di + bb1.y, 0.f);
        float h6 = fmaxf(c3.x * di + bb1.z, 0.f);
        float h7 = fmaxf(c3.y * di + bb1.w, 0.f);
        // hb = dinv * h (source weight for layer-2 aggregation), bf16-packed
        uint4 st;
        st.x = (uint_t)f2bf(h0 * di) | ((uint_t)f2bf(h1 * di) << 16);
        st.y = (uint_t)f2bf(h2 * di) | ((uint_t)f2bf(h3 * di) << 16);
        st.z = (uint_t)f2bf(h4 * di) | ((uint_t)f2bf(h5 * di) << 16);
        st.w = (uint_t)f2bf(h6 * di) | ((uint_t)f2bf(h7 * di) << 16);
        *(uint4*)(hb + (size_t)node * HID + ol * 8) = st;
    }
}

// ---- agg2 + fused GEMM2: octet gather over hb rows, then same-wave LDS dot ----
// (round-6 structure, best measured). hagg stays in LDS; out written directly.
__global__ __launch_bounds__(256) void k_agg2(
    const int* __restrict__ row_start, const uint_t* __restrict__ es,
    const float* __restrict__ dinv, const uint_t* __restrict__ hbu,
    const float* __restrict__ W2, const float* __restrict__ b2,
    float* __restrict__ out, int n)
{
    __shared__ float wsm[HID * NC];   // 10 KB, W2 row-major [64][40]
    __shared__ float hsm[32][68];     // 32 nodes x 64ch (+pad)
    for (int i = threadIdx.x; i < HID * NC; i += 256) wsm[i] = W2[i];
    __syncthreads();

    int lane = threadIdx.x & 63;
    int obase = lane & 56;
    int ol = lane & 7;
    int slot = threadIdx.x >> 3;        // node slot within block (0..31)
    int node = blockIdx.x * 32 + slot;
    bool valid = node < n;
    int rs = valid ? row_start[node] : 0;
    int re = valid ? row_start[node + 1] : 0;
    float di = valid ? dinv[node] : 0.f;
    int selfrow = valid ? node : n;

    f32x2 c0, c1, c2, c3;
    {
        uint4 sp = *(const uint4*)(hbu + (size_t)selfrow * 32 + ol * 4);
        c0 = (f32x2){0.f, 0.f}; c1 = c0; c2 = c0; c3 = c0;
        acc2(c0, sp.x); acc2(c1, sp.y); acc2(c2, sp.z); acc2(c3, sp.w);
    }
    for (int base = rs; base < re; base += 8) {
        int idx = base + ol;
        int el = (idx < re) ? (int)es[idx] : n;   // pad -> zero sentinel
        uint4 p[8];
#pragma unroll
        for (int b = 0; b < 8; ++b) {
            int s = __shfl(el, obase + b);
            p[b] = *(const uint4*)(hbu + (size_t)s * 32 + ol * 4);
        }
#pragma unroll
        for (int b = 0; b < 8; ++b) {
            acc2(c0, p[b].x); acc2(c1, p[b].y);
            acc2(c2, p[b].z); acc2(c3, p[b].w);
        }
    }
    // hagg row (f32) -> LDS; garbage for invalid nodes (never stored to out)
    {
        float4 g0, g1;
        g0.x = c0.x * di; g0.y = c0.y * di; g0.z = c1.x * di; g0.w = c1.y * di;
        g1.x = c2.x * di; g1.y = c2.y * di; g1.z = c3.x * di; g1.w = c3.y * di;
        *(float4*)&hsm[slot][ol * 8] = g0;
        *(float4*)&hsm[slot][ol * 8 + 4] = g1;
    }
    // fused GEMM2: two passes of 4-node quarter-wave dot over the wave's rows
    int w8 = (threadIdx.x >> 6) * 8;    // wave's first slot
    int qm = lane >> 4;                 // quarter 0..3
    int lq = lane & 15;
    int lw = (lq < 10) ? lq : 0;
    const float4* w4 = (const float4*)wsm;     // [64][10] float4
#pragma unroll
    for (int pass = 0; pass < 2; ++pass) {
        int slot2 = w8 + pass * 4 + qm;
        int node2 = blockIdx.x * 32 + slot2;
        float4 acc = ((const float4*)b2)[lw];  // b2 as accumulator init
#pragma unroll 4
        for (int k4 = 0; k4 < 16; ++k4) {
            float4 hk = *(const float4*)&hsm[slot2][k4 * 4];
            float4 w0 = w4[(k4 * 4 + 0) * 10 + lw];
            float4 w1 = w4[(k4 * 4 + 1) * 10 + lw];
            float4 w2 = w4[(k4 * 4 + 2) * 10 + lw];
            float4 w3 = w4[(k4 * 4 + 3) * 10 + lw];
            acc.x += hk.x * w0.x + hk.y * w1.x + hk.z * w2.x + hk.w * w3.x;
            acc.y += hk.x * w0.y + hk.y * w1.y + hk.z * w2.y + hk.w * w3.y;
            acc.z += hk.x * w0.z + hk.y * w1.z + hk.z * w2.z + hk.w * w3.z;
            acc.w += hk.x * w0.w + hk.y * w1.w + hk.z * w2.w + hk.w * w3.w;
        }
        if (node2 < n && lq < 10)
            *(float4*)(out + (size_t)node2 * NC + lq * 4) = acc;
    }
}

extern "C" void kernel_launch(void* const* d_in, const int* in_sizes, int n_in,
                              void* d_out, int out_size, void* d_ws, size_t ws_size,
                              hipStream_t stream) {
    const float* x  = (const float*)d_in[0];   // f32 [N,128]
    const int* edge = (const int*)d_in[1];     // int32 [2,E]
    const float* W1 = (const float*)d_in[2];   // f32 [128,64]
    const float* b1 = (const float*)d_in[3];   // f32 [64]
    const float* W2 = (const float*)d_in[4];   // f32 [64,40]
    const float* b2 = (const float*)d_in[5];   // f32 [40]
    float* out      = (float*)d_out;           // f32 [N,40]

    const int n = in_sizes[0] / IN_CH;   // 100000
    const int e = in_sizes[1] / 2;       // 1600000
    const int* srcs = edge;
    const int* dsts = edge + e;

    // workspace layout (all segments 16B-aligned)
    int*      gcur      = (int*)d_ws;                       // 256
    int*      row_start = gcur + 256;                       // NPAD (needs n+1)
    float*    dinv      = (float*)(row_start + NPAD);       // NPAD
    uint_t*   tmp       = (uint_t*)(dinv + NPAD);           // NBUK*CAP packed 4B
    uint_t*   es        = tmp + (size_t)NBUK * CAP;         // NEDGES src-only 4B
    ushort_t* Wp        = (ushort_t*)(es + NEDGES);         // 8192 bf16
    ushort_t* hw1       = Wp + 8192;                        // (N+1)*64 bf16 (sentinel row n)
    ushort_t* hb        = hw1 + (size_t)(NNODES + 1) * HID; // (N+1)*64 bf16 (sentinel row n)

    hipMemsetAsync(gcur, 0, NBUK * sizeof(int), stream);    // count-only cursors
    k_bin0<<<NBIN + 1, 256, 0, stream>>>(srcs, dsts, gcur, tmp, e, W1, Wp, hb, n);
    k_sort<<<NBUK, 256, 0, stream>>>(tmp, gcur, row_start, dinv, es, n, e);
    k_gemm1<<<(n + 63) / 64, 256, 0, stream>>>(x, Wp, dinv, hw1, n);
    k_agg1<<<(n + 31) / 32, 256, 0, stream>>>(row_start, es, dinv, (const uint_t*)hw1, b1, hb, n);
    k_agg2<<<(n + 31) / 32, 256, 0, stream>>>(row_start, es, dinv, (const uint_t*)hb, W2, b2, out, n);
}

// Round 10
// 210.179 us; speedup vs baseline: 1.2631x; 1.0185x over previous
//
#include <hip/hip_runtime.h>
#include <hip/hip_bf16.h>

#define NNODES 100000
#define NEDGES 1600000
#define IN_CH 128
#define HID 64
#define NC 40
#define NPAD 100352   // NNODES padded to multiple of 256
#define NBUK 196      // ceil(100000 / 512) dst-buckets of 512 nodes
#define CAP 9216      // per-bucket tmp capacity (mean 8192, sigma ~90 -> 11 sigma)
#define BCHUNK 4096
#define NBIN 391      // ceil(NEDGES / BCHUNK)

typedef unsigned short ushort_t;
typedef unsigned int uint_t;
typedef __attribute__((ext_vector_type(8))) short short8;
typedef __attribute__((ext_vector_type(4))) float floatx4;
typedef __attribute__((ext_vector_type(2))) float f32x2;

__device__ __forceinline__ ushort_t f2bf(float f) {
    union { float ff; unsigned int i; } t;
    t.ff = f;
    unsigned int r = t.i + 0x7fff + ((t.i >> 16) & 1);  // RNE
    return (ushort_t)(r >> 16);
}
// acc += unpack(packed bf16x2); vector += encourages v_pk_add_f32
__device__ __forceinline__ void acc2(f32x2& a, uint_t p) {
    union { unsigned int i; float f; } lo, hi;
    lo.i = p << 16;
    hi.i = p & 0xffff0000u;
    f32x2 v = {lo.f, hi.f};
    a += v;
}

// ---- bin edges into bucket-major tmp; entry: src(17b) | local_d(9b)<<17 ----
// gcur is count-only (zeroed by hipMemsetAsync); segment base = b*CAP + count.
// Block-local bucket sort in LDS before write-out, so tmp stores are
// contiguous runs per bucket (round-8 PMC: scattered 4B stores cost 58 MB
// WRITE_SIZE for 6.4 MB of data -> ~9x write amplification).
// Extra block (blockIdx == NBIN): Wp swizzle + hb zero-sentinel (row n).
__global__ __launch_bounds__(256) void k_bin0(
    const int* __restrict__ srcs, const int* __restrict__ dsts,
    int* __restrict__ gcur, uint_t* __restrict__ tmp, int e,
    const float* __restrict__ W1, ushort_t* __restrict__ Wp,
    ushort_t* __restrict__ hb, int n)
{
    __shared__ uint_t pk[BCHUNK];    // 16 KB (input order)
    __shared__ ushort_t bk[BCHUNK];  // 8 KB
    __shared__ uint_t spk[BCHUNK];   // 16 KB (bucket-sorted)
    __shared__ ushort_t sb[BCHUNK];  // 8 KB bucket id per sorted slot
    __shared__ int hist[NBUK];
    __shared__ int lscan[NBUK];      // local exclusive scan over buckets
    __shared__ int base[NBUK];       // global base per bucket
    __shared__ int sc2[256];
    int t = threadIdx.x;
    if (blockIdx.x >= NBIN) {        // side-work block (uniform branch)
        for (int i = t; i < IN_CH * HID; i += 256) {
            int j = i & 7;
            int m = (i >> 3) & 15;
            int ct = (i >> 7) & 3;
            int quad = (i >> 9) & 3;
            int kc = i >> 11;
            int k = kc * 32 + quad * 8 + j;
            int c = ct * 16 + m;
            Wp[i] = f2bf(W1[k * HID + c]);
        }
        uint_t* hbz = (uint_t*)(hb + (size_t)n * HID);
        if (t < 32) hbz[t] = 0;      // 64 bf16 zeros (sentinel row n)
        return;
    }
    int begin = blockIdx.x * BCHUNK;
    int cnt = e - begin; if (cnt > BCHUNK) cnt = BCHUNK;

    for (int i = t; i < NBUK; i += 256) hist[i] = 0;
    __syncthreads();
    // pass 1: load + per-bucket count
    for (int j = t; j < cnt; j += 256) {
        int d = dsts[begin + j];
        int s = srcs[begin + j];
        int b = d >> 9;
        pk[j] = (uint_t)s | ((uint_t)(d & 511) << 17);
        bk[j] = (ushort_t)b;
        atomicAdd(&hist[b], 1);
    }
    __syncthreads();
    // pass 2: local scan (196 buckets) + global segment reservation
    int c = (t < NBUK) ? hist[t] : 0;
    sc2[t] = c;
    __syncthreads();
    for (int off = 1; off < 256; off <<= 1) {
        int v = (t >= off) ? sc2[t - off] : 0;
        __syncthreads();
        sc2[t] += v;
        __syncthreads();
    }
    if (t < NBUK) {
        lscan[t] = sc2[t] - c;
        base[t] = t * CAP + atomicAdd(&gcur[t], c);
        hist[t] = 0;                 // reuse as rank cursor
    }
    __syncthreads();
    // pass 3: rank-scatter into sorted LDS buffer
    for (int j = t; j < cnt; j += 256) {
        int b = bk[j];
        int r = atomicAdd(&hist[b], 1);
        int slot = lscan[b] + r;
        spk[slot] = pk[j];
        sb[slot] = (ushort_t)b;
    }
    __syncthreads();
    // pass 4: linear write-out (contiguous run per bucket)
    for (int j = t; j < cnt; j += 256) {
        int b = sb[j];
        int pos = base[b] + (j - lscan[b]);
        if (pos < (b + 1) * CAP) tmp[pos] = spk[j];  // guard vs overflow
    }
}

// ---- merged sort: per-bucket count + scan + row_start/dinv + scatter to es ----
// Scatter to LDS staging (block's whole output segment), then fully
// coalesced linear copy to es (kills the random-4B-store write amplification).
__global__ __launch_bounds__(256) void k_sort(
    const uint_t* __restrict__ tmp, const int* __restrict__ gcur,
    int* __restrict__ row_start, float* __restrict__ dinv,
    uint_t* __restrict__ es, int n, int e)
{
    __shared__ int cnt[512];
    __shared__ int sc[512];
    __shared__ int red[256];
    __shared__ uint_t esl[CAP];   // 36 KB staging (total <= CAP)
    int t = threadIdx.x;
    int b = blockIdx.x;
    int d0 = b << 9;
    int total = gcur[b];
    if (total > CAP) total = CAP;
    // gb = exclusive prefix over bucket totals
    int part = 0;
    for (int i = t; i < b; i += 256) part += gcur[i];
    red[t] = part;
    cnt[t] = 0; cnt[t + 256] = 0;
    __syncthreads();
    for (int off = 128; off > 0; off >>= 1) {
        if (t < off) red[t] += red[t + off];
        __syncthreads();
    }
    int gb = red[0];
    // count per node
    const uint_t* seg = tmp + b * CAP;
    for (int j = t; j < total; j += 256)
        atomicAdd(&cnt[seg[j] >> 17], 1);
    __syncthreads();
    sc[t] = cnt[t]; sc[t + 256] = cnt[t + 256];
    __syncthreads();
    for (int off = 1; off < 512; off <<= 1) {
        int v0 = (t >= off) ? sc[t - off] : 0;
        int i1 = t + 256;
        int v1 = (i1 >= off) ? sc[i1 - off] : 0;
        __syncthreads();
        sc[t] += v0; sc[i1] += v1;
        __syncthreads();
    }
#pragma unroll
    for (int q = 0; q < 2; ++q) {
        int i = t + q * 256;
        int node = d0 + i;
        int start = gb + sc[i] - cnt[i];
        if (node < n) {
            row_start[node] = start;
            dinv[node] = rsqrtf((float)cnt[i] + 1.0f);
        }
        cnt[i] = start - gb;   // reuse cnt as LOCAL scatter cursor (segment-relative)
    }
    __syncthreads();
    // scatter to LDS staging in final CSR order
    for (int j = t; j < total; j += 256) {
        uint_t p = seg[j];
        int ld = (int)(p >> 17);
        int pos = atomicAdd(&cnt[ld], 1);
        esl[pos] = p & 0x1FFFFu;
    }
    __syncthreads();
    // coalesced linear write-out
    for (int j = t; j < total; j += 256) es[gb + j] = esl[j];
    if (b == NBUK - 1 && t == 0) row_start[n] = e;
}

// ---- GEMM1: hw1 = bf16(dinv * (x @ W1)) via MFMA; row n = zero sentinel ----
__global__ __launch_bounds__(256) void k_gemm1(
    const float* __restrict__ x, const ushort_t* __restrict__ Wp,
    const float* __restrict__ dinv, ushort_t* __restrict__ hw1, int n)
{
    int wave = threadIdx.x >> 6;
    int lane = threadIdx.x & 63;
    int m = lane & 15;
    int quad = lane >> 4;
    int row = blockIdx.x * 64 + wave * 16 + m;
    int rowc = row < n ? row : (n - 1);
    const float* xr = x + (size_t)rowc * IN_CH + quad * 8;

    floatx4 acc[4];
#pragma unroll
    for (int ct = 0; ct < 4; ++ct) acc[ct] = (floatx4){0.f, 0.f, 0.f, 0.f};

#pragma unroll
    for (int kc = 0; kc < 4; ++kc) {
        float4 xa = *(const float4*)(xr + kc * 32);
        float4 xb = *(const float4*)(xr + kc * 32 + 4);
        short8 a;
        a[0] = (short)f2bf(xa.x); a[1] = (short)f2bf(xa.y);
        a[2] = (short)f2bf(xa.z); a[3] = (short)f2bf(xa.w);
        a[4] = (short)f2bf(xb.x); a[5] = (short)f2bf(xb.y);
        a[6] = (short)f2bf(xb.z); a[7] = (short)f2bf(xb.w);
#pragma unroll
        for (int ct = 0; ct < 4; ++ct) {
            short8 b = *(const short8*)(Wp + ((((kc * 4 + quad) * 4 + ct) * 16 + m) << 3));
            acc[ct] = __builtin_amdgcn_mfma_f32_16x16x32_bf16(a, b, acc[ct], 0, 0, 0);
        }
    }
    int r0 = blockIdx.x * 64 + wave * 16 + quad * 4;
#pragma unroll
    for (int r = 0; r < 4; ++r) {
        int rr = r0 + r;
        if (rr < n) {
            float di = dinv[rr];
            ushort_t* o = hw1 + (size_t)rr * HID + m;
#pragma unroll
            for (int ct = 0; ct < 4; ++ct) o[ct * 16] = f2bf(acc[ct][r] * di);
        } else if (rr == n) {
            ushort_t* o = hw1 + (size_t)n * HID + m;
#pragma unroll
            for (int ct = 0; ct < 4; ++ct) o[ct * 16] = 0;
        }
    }
}

// ---- agg1: one OCTET (8 lanes) per node ----
// NEW vs round 9: __launch_bounds__(256,4) raises the VGPR budget to 128 so
// the compiler keeps all 8 p[] gathers in flight (round-9 VGPR=32 proved it
// was serializing them to ~2), and the next window's es indices are
// prefetched while the current window is consumed (takes the es-load latency
// off the head of every window chain). Structure otherwise identical.
__global__ __launch_bounds__(256, 4) void k_agg1(
    const int* __restrict__ row_start, const uint_t* __restrict__ es,
    const float* __restrict__ dinv, const uint_t* __restrict__ hw1u,
    const float* __restrict__ b1, ushort_t* __restrict__ hb, int n)
{
    int lane = threadIdx.x & 63;
    int obase = lane & 56;              // octet's first lane in the wave
    int ol = lane & 7;
    int node = blockIdx.x * 32 + (threadIdx.x >> 3);
    bool valid = node < n;
    int rs = valid ? row_start[node] : 0;
    int re = valid ? row_start[node + 1] : 0;
    float di = valid ? dinv[node] : 0.f;
    int selfrow = valid ? node : n;

    f32x2 c0, c1, c2, c3;
    {
        uint4 sp = *(const uint4*)(hw1u + (size_t)selfrow * 32 + ol * 4);
        c0 = (f32x2){0.f, 0.f}; c1 = c0; c2 = c0; c3 = c0;
        acc2(c0, sp.x); acc2(c1, sp.y); acc2(c2, sp.z); acc2(c3, sp.w);
    }
    int el = n;
    if (rs < re) {
        int idx = rs + ol;
        el = (idx < re) ? (int)es[idx] : n;   // pad -> zero sentinel
    }
    for (int base = rs; base < re; base += 8) {
        int el_cur = el;
        int nb = base + 8;
        if (nb < re) {                         // prefetch next window's indices
            int idx = nb + ol;
            el = (idx < re) ? (int)es[idx] : n;
        }
        uint4 p[8];
#pragma unroll
        for (int b = 0; b < 8; ++b) {
            int s = __shfl(el_cur, obase + b);
            p[b] = *(const uint4*)(hw1u + (size_t)s * 32 + ol * 4);
        }
#pragma unroll
        for (int b = 0; b < 8; ++b) {
            acc2(c0, p[b].x); acc2(c1, p[b].y);
            acc2(c2, p[b].z); acc2(c3, p[b].w);
        }
    }
    if (valid) {
        float4 bb0 = ((const float4*)b1)[ol * 2];
        float4 bb1 = ((const float4*)b1)[ol * 2 + 1];
        float h0 = fmaxf(c0.x * di + bb0.x, 0.f);
        float h1 = fmaxf(c0.y * di + bb0.y, 0.f);
        float h2 = fmaxf(c1.x * di + bb0.z, 0.f);
        float h3 = fmaxf(c1.y * di + bb0.w, 0.f);
        float h4 = fmaxf(c2.x * di + bb1.x, 0.f);
        float h5 = fmaxf(c2.y * di + bb1.y, 0.f);
        float h6 = fmaxf(c3.x * di + bb1.z, 0.f);
        float h7 = fmaxf(c3.y * di + bb1.w, 0.f);
        // hb = dinv * h (source weight for layer-2 aggregation), bf16-packed
        uint4 st;
        st.x = (uint_t)f2bf(h0 * di) | ((uint_t)f2bf(h1 * di) << 16);
        st.y = (uint_t)f2bf(h2 * di) | ((uint_t)f2bf(h3 * di) << 16);
        st.z = (uint_t)f2bf(h4 * di) | ((uint_t)f2bf(h5 * di) << 16);
        st.w = (uint_t)f2bf(h6 * di) | ((uint_t)f2bf(h7 * di) << 16);
        *(uint4*)(hb + (size_t)node * HID + ol * 8) = st;
    }
}

// ---- agg2 + fused GEMM2: octet gather over hb rows, then same-wave LDS dot ----
// Same (256,4) + es-prefetch treatment as agg1; dot epilogue unchanged.
__global__ __launch_bounds__(256, 4) void k_agg2(
    const int* __restrict__ row_start, const uint_t* __restrict__ es,
    const float* __restrict__ dinv, const uint_t* __restrict__ hbu,
    const float* __restrict__ W2, const float* __restrict__ b2,
    float* __restrict__ out, int n)
{
    __shared__ float wsm[HID * NC];   // 10 KB, W2 row-major [64][40]
    __shared__ float hsm[32][68];     // 32 nodes x 64ch (+pad)
    for (int i = threadIdx.x; i < HID * NC; i += 256) wsm[i] = W2[i];
    __syncthreads();

    int lane = threadIdx.x & 63;
    int obase = lane & 56;
    int ol = lane & 7;
    int slot = threadIdx.x >> 3;        // node slot within block (0..31)
    int node = blockIdx.x * 32 + slot;
    bool valid = node < n;
    int rs = valid ? row_start[node] : 0;
    int re = valid ? row_start[node + 1] : 0;
    float di = valid ? dinv[node] : 0.f;
    int selfrow = valid ? node : n;

    f32x2 c0, c1, c2, c3;
    {
        uint4 sp = *(const uint4*)(hbu + (size_t)selfrow * 32 + ol * 4);
        c0 = (f32x2){0.f, 0.f}; c1 = c0; c2 = c0; c3 = c0;
        acc2(c0, sp.x); acc2(c1, sp.y); acc2(c2, sp.z); acc2(c3, sp.w);
    }
    int el = n;
    if (rs < re) {
        int idx = rs + ol;
        el = (idx < re) ? (int)es[idx] : n;   // pad -> zero sentinel
    }
    for (int base = rs; base < re; base += 8) {
        int el_cur = el;
        int nb = base + 8;
        if (nb < re) {                         // prefetch next window's indices
            int idx = nb + ol;
            el = (idx < re) ? (int)es[idx] : n;
        }
        uint4 p[8];
#pragma unroll
        for (int b = 0; b < 8; ++b) {
            int s = __shfl(el_cur, obase + b);
            p[b] = *(const uint4*)(hbu + (size_t)s * 32 + ol * 4);
        }
#pragma unroll
        for (int b = 0; b < 8; ++b) {
            acc2(c0, p[b].x); acc2(c1, p[b].y);
            acc2(c2, p[b].z); acc2(c3, p[b].w);
        }
    }
    // hagg row (f32) -> LDS; garbage for invalid nodes (never stored to out)
    {
        float4 g0, g1;
        g0.x = c0.x * di; g0.y = c0.y * di; g0.z = c1.x * di; g0.w = c1.y * di;
        g1.x = c2.x * di; g1.y = c2.y * di; g1.z = c3.x * di; g1.w = c3.y * di;
        *(float4*)&hsm[slot][ol * 8] = g0;
        *(float4*)&hsm[slot][ol * 8 + 4] = g1;
    }
    // fused GEMM2: two passes of 4-node quarter-wave dot over the wave's rows
    int w8 = (threadIdx.x >> 6) * 8;    // wave's first slot
    int qm = lane >> 4;                 // quarter 0..3
    int lq = lane & 15;
    int lw = (lq < 10) ? lq : 0;
    const float4* w4 = (const float4*)wsm;     // [64][10] float4
#pragma unroll
    for (int pass = 0; pass < 2; ++pass) {
        int slot2 = w8 + pass * 4 + qm;
        int node2 = blockIdx.x * 32 + slot2;
        float4 acc = ((const float4*)b2)[lw];  // b2 as accumulator init
#pragma unroll 4
        for (int k4 = 0; k4 < 16; ++k4) {
            float4 hk = *(const float4*)&hsm[slot2][k4 * 4];
            float4 w0 = w4[(k4 * 4 + 0) * 10 + lw];
            float4 w1 = w4[(k4 * 4 + 1) * 10 + lw];
            float4 w2 = w4[(k4 * 4 + 2) * 10 + lw];
            float4 w3 = w4[(k4 * 4 + 3) * 10 + lw];
            acc.x += hk.x * w0.x + hk.y * w1.x + hk.z * w2.x + hk.w * w3.x;
            acc.y += hk.x * w0.y + hk.y * w1.y + hk.z * w2.y + hk.w * w3.y;
            acc.z += hk.x * w0.z + hk.y * w1.z + hk.z * w2.z + hk.w * w3.z;
            acc.w += hk.x * w0.w + hk.y * w1.w + hk.z * w2.w + hk.w * w3.w;
        }
        if (node2 < n && lq < 10)
            *(float4*)(out + (size_t)node2 * NC + lq * 4) = acc;
    }
}

extern "C" void kernel_launch(void* const* d_in, const int* in_sizes, int n_in,
                              void* d_out, int out_size, void* d_ws, size_t ws_size,
                              hipStream_t stream) {
    const float* x  = (const float*)d_in[0];   // f32 [N,128]
    const int* edge = (const int*)d_in[1];     // int32 [2,E]
    const float* W1 = (const float*)d_in[2];   // f32 [128,64]
    const float* b1 = (const float*)d_in[3];   // f32 [64]
    const float* W2 = (const float*)d_in[4];   // f32 [64,40]
    const float* b2 = (const float*)d_in[5];   // f32 [40]
    float* out      = (float*)d_out;           // f32 [N,40]

    const int n = in_sizes[0] / IN_CH;   // 100000
    const int e = in_sizes[1] / 2;       // 1600000
    const int* srcs = edge;
    const int* dsts = edge + e;

    // workspace layout (all segments 16B-aligned)
    int*      gcur      = (int*)d_ws;                       // 256
    int*      row_start = gcur + 256;                       // NPAD (needs n+1)
    float*    dinv      = (float*)(row_start + NPAD);       // NPAD
    uint_t*   tmp       = (uint_t*)(dinv + NPAD);           // NBUK*CAP packed 4B
    uint_t*   es        = tmp + (size_t)NBUK * CAP;         // NEDGES src-only 4B
    ushort_t* Wp        = (ushort_t*)(es + NEDGES);         // 8192 bf16
    ushort_t* hw1       = Wp + 8192;                        // (N+1)*64 bf16 (sentinel row n)
    ushort_t* hb        = hw1 + (size_t)(NNODES + 1) * HID; // (N+1)*64 bf16 (sentinel row n)

    hipMemsetAsync(gcur, 0, NBUK * sizeof(int), stream);    // count-only cursors
    k_bin0<<<NBIN + 1, 256, 0, stream>>>(srcs, dsts, gcur, tmp, e, W1, Wp, hb, n);
    k_sort<<<NBUK, 256, 0, stream>>>(tmp, gcur, row_start, dinv, es, n, e);
    k_gemm1<<<(n + 63) / 64, 256, 0, stream>>>(x, Wp, dinv, hw1, n);
    k_agg1<<<(n + 31) / 32, 256, 0, stream>>>(row_start, es, dinv, (const uint_t*)hw1, b1, hb, n);
    k_agg2<<<(n + 31) / 32, 256, 0, stream>>>(row_start, es, dinv, (const uint_t*)hb, W2, b2, out, n);
}